// Round 2
// baseline (1102.499 us; speedup 1.0000x reference)
//
#include <hip/hip_runtime.h>
#include <hip/hip_bf16.h>

typedef unsigned short u16;
typedef unsigned int   u32;
typedef __attribute__((ext_vector_type(8))) short bf16x8;
typedef __attribute__((ext_vector_type(4))) float f32x4;

#define NTOK 32768
#define TPB  4          // tokens per block (attn/ffn kernels)
#define MR   36         // real rows per block (TPB*9)
#define MPAD 48         // padded to 3 MFMA M-tiles
#define NBLK (NTOK/TPB) // 8192

__device__ __forceinline__ float bf2f(u16 u) {
    u32 x = ((u32)u) << 16; float f; __builtin_memcpy(&f, &x, 4); return f;
}
__device__ __forceinline__ u16 f2bf(float f) {
    u32 u; __builtin_memcpy(&u, &f, 4);
    u32 r = (u + 0x7fffu + ((u >> 16) & 1u)) >> 16;
    return (u16)r;
}
__device__ __forceinline__ float wredsum(float v) {
#pragma unroll
    for (int m = 32; m >= 1; m >>= 1) v += __shfl_xor(v, m, 64);
    return v;
}

// ---------------- weight fp32 -> bf16 ----------------
// wbf layout (u16 elems): [0,98304) wqkv (2x384x128) | [98304,131072) wo (2x128x128)
//                         [131072,196608) w1 (2x256x128) | [196608,262144) w2 (2x128x256)
__global__ __launch_bounds__(256) void k_wconv(const float* __restrict__ wqkv, const float* __restrict__ wo,
                                               const float* __restrict__ w1, const float* __restrict__ w2,
                                               u16* __restrict__ wbf) {
    int i = blockIdx.x * 256 + threadIdx.x; // grid 1024 -> 262144 exact
    float v;
    if (i < 98304)       v = wqkv[i];
    else if (i < 131072) v = wo[i - 98304];
    else if (i < 196608) v = w1[i - 131072];
    else                 v = w2[i - 196608];
    wbf[i] = f2bf(v);
}

// ---------------- embedding: e[b][h][w][d] ----------------
__global__ __launch_bounds__(256) void k_embed(const float* __restrict__ x, const float* __restrict__ ew,
                                               const float* __restrict__ eb, float* __restrict__ e) {
    int idx = blockIdx.x * 256 + threadIdx.x; // grid 16384 -> 4194304 exact
    int d = idx & 127, pix = idx >> 7;
    int b = pix >> 14, hw = pix & 16383;
    const float* xp = x + b * 262144 + hw;    // x[b][c][h][w], c-stride 16384
    const float* wr = ew + d * 16;
    float acc = eb[d];
#pragma unroll
    for (int c = 0; c < 16; ++c) acc += xp[c * 16384] * wr[c];
    e[idx] = acc;
}

// ---------------- window gather + pos: t[n][p][c] ----------------
__global__ __launch_bounds__(256) void k_build(const float* __restrict__ e, const float* __restrict__ pos,
                                               float* __restrict__ t) {
    int id = blockIdx.x * 256 + threadIdx.x; // grid 36864 -> 9437184 exact
    int c4 = (id & 31) << 2;
    int np = id >> 5;            // n*9+p, < 294912
    int p = np % 9;
    int n = np / 9;
    int b = n >> 14, h = (n >> 7) & 127, w = n & 127;
    int sh = h + p / 3 - 1, sw = w + p % 3 - 1;
    float4 v = {0.f, 0.f, 0.f, 0.f};
    if (sh >= 0 && sh < 128 && sw >= 0 && sw < 128)
        v = *(const float4*)(e + (size_t)((b << 14) + (sh << 7) + sw) * 128 + c4);
    float4 pv = *(const float4*)(pos + p * 128 + c4);
    v.x += pv.x; v.y += pv.y; v.z += pv.z; v.w += pv.w;
    *(float4*)(t + (size_t)np * 128 + c4) = v;
}

// ---------------- layer part 1: LN1 + qkv + attention + wo + residual ----------------
// LDS tiles are XOR-swizzled: byte-in-row ^ ((row&7)<<4), consistent on write & read.
__global__ __launch_bounds__(256) void k_attn(
    float* __restrict__ t,
    const u16* __restrict__ wq, const float* __restrict__ bq,
    const u16* __restrict__ wov, const float* __restrict__ bov,
    const float* __restrict__ lg, const float* __restrict__ lb) {
    __shared__ char hb[MPAD * 256];  // bf16[48][128]: LN out, then attention out o
    __shared__ char qk[MPAD * 768];  // bf16[48][384]: q(scaled)|k|v
    const int tid = threadIdx.x, lane = tid & 63, wid = tid >> 6;
    const int blk = blockIdx.x;
    const int col = lane & 15, grp = lane >> 4;

    // zero pad rows 36..47 of hb (keeps padded M-tiles finite & deterministic)
    if (tid < 192) {
        int pr = MR + (tid >> 4), pc = (tid & 15) * 16;
        f32x4 z = {0.f, 0.f, 0.f, 0.f};
        *(f32x4*)(hb + pr * 256 + (pc ^ ((pr & 7) << 4))) = z;
    }
    // Phase 1: LayerNorm -> hb (bf16)
    {
        float2 gv = ((const float2*)lg)[lane];
        float2 bv = ((const float2*)lb)[lane];
        for (int r = wid; r < MR; r += 4) {
            const float2* tr = (const float2*)(t + ((size_t)blk * MR + r) * 128);
            float2 xv = tr[lane];
            float mean = wredsum(xv.x + xv.y) * (1.f / 128.f);
            float var  = wredsum(xv.x * xv.x + xv.y * xv.y) * (1.f / 128.f) - mean * mean;
            float rstd = rsqrtf(var + 1e-5f);
            float h0 = (xv.x - mean) * rstd * gv.x + bv.x;
            float h1 = (xv.y - mean) * rstd * gv.y + bv.y;
            u32 pk = (u32)f2bf(h0) | ((u32)f2bf(h1) << 16);
            *(u32*)(hb + r * 256 + ((lane * 4) ^ ((r & 7) << 4))) = pk;
        }
    }
    __syncthreads();
    // Phase 2: qkv GEMM (M=48, N=384, K=128). q gets bias then *scale.
    for (int nt = 0; nt < 6; ++nt) {
        int n0 = (wid * 6 + nt) * 16;
        int nr = n0 + col;
        bf16x8 bfr[4];
        const u16* wr = wq + nr * 128 + grp * 8;
#pragma unroll
        for (int ks = 0; ks < 4; ++ks) bfr[ks] = *(const bf16x8*)(wr + ks * 32);
        float bias = bq[nr];
        float scl = (n0 < 128) ? 0.17677669529663687f : 1.0f;
        for (int mt = 0; mt < 3; ++mt) {
            f32x4 acc = {0.f, 0.f, 0.f, 0.f};
#pragma unroll
            for (int ks = 0; ks < 4; ++ks) {
                int row = mt * 16 + col;
                bf16x8 a = *(const bf16x8*)(hb + row * 256 + ((ks * 64 + grp * 16) ^ ((row & 7) << 4)));
                acc = __builtin_amdgcn_mfma_f32_16x16x32_bf16(a, bfr[ks], acc, 0, 0, 0);
            }
#pragma unroll
            for (int j = 0; j < 4; ++j) {
                int R = mt * 16 + grp * 4 + j;
                float v = (acc[j] + bias) * scl;
                *(u16*)(qk + R * 768 + ((nr * 2) ^ ((R & 7) << 4))) = f2bf(v);
            }
        }
    }
    __syncthreads();
    // Phase 3: attention. Each wave owns one token (4 heads). o -> hb.
    {
        int tok = wid;
        int rb = tok * 9;
        for (int head = 0; head < 4; ++head) {
            int rq = rb + (col < 9 ? col : 0); // clamp padded rows/cols
            bf16x8 aq = *(const bf16x8*)(qk + rq * 768 + ((head * 64 + grp * 16) ^ ((rq & 7) << 4)));
            bf16x8 bk = *(const bf16x8*)(qk + rq * 768 + ((256 + head * 64 + grp * 16) ^ ((rq & 7) << 4)));
            f32x4 z = {0.f, 0.f, 0.f, 0.f};
            f32x4 s = __builtin_amdgcn_mfma_f32_16x16x32_bf16(aq, bk, z, 0, 0, 0);
            // lane holds scores[row = grp*4+q4][colj = col]
            bool jv = (col < 9);
            float att[4], red[4];
#pragma unroll
            for (int q4 = 0; q4 < 4; ++q4) red[q4] = jv ? s[q4] : -1e30f;
#pragma unroll
            for (int m = 8; m >= 1; m >>= 1)
#pragma unroll
                for (int q4 = 0; q4 < 4; ++q4) red[q4] = fmaxf(red[q4], __shfl_xor(red[q4], m, 64));
#pragma unroll
            for (int q4 = 0; q4 < 4; ++q4) att[q4] = jv ? __expf(s[q4] - red[q4]) : 0.f;
#pragma unroll
            for (int q4 = 0; q4 < 4; ++q4) red[q4] = att[q4];
#pragma unroll
            for (int m = 8; m >= 1; m >>= 1)
#pragma unroll
                for (int q4 = 0; q4 < 4; ++q4) red[q4] += __shfl_xor(red[q4], m, 64);
#pragma unroll
            for (int q4 = 0; q4 < 4; ++q4) att[q4] /= red[q4];
            // PV (VALU): o[i][d] = sum_j att[i][j] * v[j][d]
            int d = lane & 31, ih = lane >> 5;
            float vj[9];
#pragma unroll
            for (int j = 0; j < 9; ++j) {
                int row = rb + j;
                vj[j] = bf2f(*(const u16*)(qk + row * 768 + ((512 + head * 64 + d * 2) ^ ((row & 7) << 4))));
            }
            int srcb = ih * 16;
#pragma unroll
            for (int ip = 0; ip < 4; ++ip) { // i = ip + ih*4 (rows 0..7)
                float oacc = 0.f;
#pragma unroll
                for (int j = 0; j < 9; ++j) oacc += __shfl(att[ip], srcb + j, 64) * vj[j];
                int row = rb + ip + ih * 4;
                *(u16*)(hb + row * 256 + ((head * 64 + d * 2) ^ ((row & 7) << 4))) = f2bf(oacc);
            }
            { // i = 8: att row 8 lives at lanes 32..47, reg 0
                float oacc = 0.f;
#pragma unroll
                for (int j = 0; j < 9; ++j) oacc += __shfl(att[0], 32 + j, 64) * vj[j];
                if (ih == 0) {
                    int row = rb + 8;
                    *(u16*)(hb + row * 256 + ((head * 64 + d * 2) ^ ((row & 7) << 4))) = f2bf(oacc);
                }
            }
        }
    }
    __syncthreads();
    // Phase 4: wo GEMM + residual (in-place t update; rows owned exclusively by this block)
    for (int nt = 0; nt < 2; ++nt) {
        int n0 = (wid * 2 + nt) * 16;
        int nr = n0 + col;
        bf16x8 bfr[4];
        const u16* wr = wov + nr * 128 + grp * 8;
#pragma unroll
        for (int ks = 0; ks < 4; ++ks) bfr[ks] = *(const bf16x8*)(wr + ks * 32);
        float bias = bov[nr];
        for (int mt = 0; mt < 3; ++mt) {
            f32x4 acc = {0.f, 0.f, 0.f, 0.f};
#pragma unroll
            for (int ks = 0; ks < 4; ++ks) {
                int row = mt * 16 + col;
                bf16x8 a = *(const bf16x8*)(hb + row * 256 + ((ks * 64 + grp * 16) ^ ((row & 7) << 4)));
                acc = __builtin_amdgcn_mfma_f32_16x16x32_bf16(a, bfr[ks], acc, 0, 0, 0);
            }
#pragma unroll
            for (int j = 0; j < 4; ++j) {
                int R = mt * 16 + grp * 4 + j;
                if (R < MR) {
                    float* p = t + ((size_t)blk * MR + R) * 128 + nr;
                    *p = acc[j] + bias + *p;
                }
            }
        }
    }
}

// ---------------- layer part 2: LN2 + FFN + residual ----------------
__global__ __launch_bounds__(256) void k_ffn(
    float* __restrict__ t,
    const u16* __restrict__ w1w, const float* __restrict__ b1v,
    const u16* __restrict__ w2w, const float* __restrict__ b2v,
    const float* __restrict__ lg, const float* __restrict__ lb) {
    __shared__ char hb[MPAD * 256];   // bf16[48][128] LN out
    __shared__ char mid[MPAD * 512];  // bf16[48][256] gelu(h@w1^T+b1)
    const int tid = threadIdx.x, lane = tid & 63, wid = tid >> 6;
    const int blk = blockIdx.x;
    const int col = lane & 15, grp = lane >> 4;

    if (tid < 192) {
        int pr = MR + (tid >> 4), pc = (tid & 15) * 16;
        f32x4 z = {0.f, 0.f, 0.f, 0.f};
        *(f32x4*)(hb + pr * 256 + (pc ^ ((pr & 7) << 4))) = z;
    }
    {
        float2 gv = ((const float2*)lg)[lane];
        float2 bv = ((const float2*)lb)[lane];
        for (int r = wid; r < MR; r += 4) {
            const float2* tr = (const float2*)(t + ((size_t)blk * MR + r) * 128);
            float2 xv = tr[lane];
            float mean = wredsum(xv.x + xv.y) * (1.f / 128.f);
            float var  = wredsum(xv.x * xv.x + xv.y * xv.y) * (1.f / 128.f) - mean * mean;
            float rstd = rsqrtf(var + 1e-5f);
            float h0 = (xv.x - mean) * rstd * gv.x + bv.x;
            float h1 = (xv.y - mean) * rstd * gv.y + bv.y;
            u32 pk = (u32)f2bf(h0) | ((u32)f2bf(h1) << 16);
            *(u32*)(hb + r * 256 + ((lane * 4) ^ ((r & 7) << 4))) = pk;
        }
    }
    __syncthreads();
    // GEMM1: M=48, N=256, K=128 + exact gelu -> mid
    for (int nt = 0; nt < 4; ++nt) {
        int n0 = (wid * 4 + nt) * 16;
        int nr = n0 + col;
        bf16x8 bfr[4];
        const u16* wr = w1w + nr * 128 + grp * 8;
#pragma unroll
        for (int ks = 0; ks < 4; ++ks) bfr[ks] = *(const bf16x8*)(wr + ks * 32);
        float bias = b1v[nr];
        for (int mt = 0; mt < 3; ++mt) {
            f32x4 acc = {0.f, 0.f, 0.f, 0.f};
#pragma unroll
            for (int ks = 0; ks < 4; ++ks) {
                int row = mt * 16 + col;
                bf16x8 a = *(const bf16x8*)(hb + row * 256 + ((ks * 64 + grp * 16) ^ ((row & 7) << 4)));
                acc = __builtin_amdgcn_mfma_f32_16x16x32_bf16(a, bfr[ks], acc, 0, 0, 0);
            }
#pragma unroll
            for (int j = 0; j < 4; ++j) {
                int R = mt * 16 + grp * 4 + j;
                float xg = acc[j] + bias;
                float ge = xg * 0.5f * (1.f + erff(xg * 0.70710678118654752f));
                *(u16*)(mid + R * 512 + ((nr * 2) ^ ((R & 7) << 4))) = f2bf(ge);
            }
        }
    }
    __syncthreads();
    // GEMM2: M=48, N=128, K=256 + residual
    for (int nt = 0; nt < 2; ++nt) {
        int n0 = (wid * 2 + nt) * 16;
        int nr = n0 + col;
        bf16x8 bfr[8];
        const u16* wr = w2w + nr * 256 + grp * 8;
#pragma unroll
        for (int ks = 0; ks < 8; ++ks) bfr[ks] = *(const bf16x8*)(wr + ks * 32);
        float bias = b2v[nr];
        for (int mt = 0; mt < 3; ++mt) {
            f32x4 acc = {0.f, 0.f, 0.f, 0.f};
#pragma unroll
            for (int ks = 0; ks < 8; ++ks) {
                int row = mt * 16 + col;
                bf16x8 a = *(const bf16x8*)(mid + row * 512 + ((ks * 64 + grp * 16) ^ ((row & 7) << 4)));
                acc = __builtin_amdgcn_mfma_f32_16x16x32_bf16(a, bfr[ks], acc, 0, 0, 0);
            }
#pragma unroll
            for (int j = 0; j < 4; ++j) {
                int R = mt * 16 + grp * 4 + j;
                if (R < MR) {
                    float* p = t + ((size_t)blk * MR + R) * 128 + nr;
                    *p = acc[j] + bias + *p;
                }
            }
        }
    }
}

// ---------------- final: center LN + head ----------------
__global__ __launch_bounds__(256) void k_head(const float* __restrict__ t, const float* __restrict__ g,
                                              const float* __restrict__ b, const float* __restrict__ hw,
                                              const float* __restrict__ hbias, float* __restrict__ out) {
    int lane = threadIdx.x & 63, wid = threadIdx.x >> 6;
    int base = blockIdx.x * 16 + wid * 4; // grid 2048 -> 32768 tokens
    float2 gv = ((const float2*)g)[lane];
    float2 bv = ((const float2*)b)[lane];
    float2 wv = ((const float2*)hw)[lane];
    float hb0 = hbias[0];
    for (int it = 0; it < 4; ++it) {
        int n = base + it;
        const float2* row = (const float2*)(t + ((size_t)n * 9 + 4) * 128);
        float2 xv = row[lane];
        float mean = wredsum(xv.x + xv.y) * (1.f / 128.f);
        float var  = wredsum(xv.x * xv.x + xv.y * xv.y) * (1.f / 128.f) - mean * mean;
        float rstd = rsqrtf(var + 1e-5f);
        float v = ((xv.x - mean) * rstd * gv.x + bv.x) * wv.x +
                  ((xv.y - mean) * rstd * gv.y + bv.y) * wv.y;
        v = wredsum(v);
        if (lane == 0) out[n] = v + hb0; // out[b*16384+h*128+w] == token index
    }
}

extern "C" void kernel_launch(void* const* d_in, const int* in_sizes, int n_in,
                              void* d_out, int out_size, void* d_ws, size_t ws_size,
                              hipStream_t stream) {
    (void)in_sizes; (void)n_in; (void)out_size; (void)ws_size;
    const float* x     = (const float*)d_in[0];
    const float* emb_w = (const float*)d_in[1];
    const float* emb_b = (const float*)d_in[2];
    const float* pos   = (const float*)d_in[3];
    const float* wqkv  = (const float*)d_in[4];
    const float* bqkv  = (const float*)d_in[5];
    const float* wo    = (const float*)d_in[6];
    const float* bo    = (const float*)d_in[7];
    const float* ln1g  = (const float*)d_in[8];
    const float* ln1b  = (const float*)d_in[9];
    const float* ln2g  = (const float*)d_in[10];
    const float* ln2b  = (const float*)d_in[11];
    const float* w1    = (const float*)d_in[12];
    const float* b1    = (const float*)d_in[13];
    const float* w2    = (const float*)d_in[14];
    const float* b2    = (const float*)d_in[15];
    const float* lnfg  = (const float*)d_in[16];
    const float* lnfb  = (const float*)d_in[17];
    const float* headw = (const float*)d_in[18];
    const float* headb = (const float*)d_in[19];
    float* out = (float*)d_out;

    // workspace: e fp32 (16 MB) | t fp32 (151 MB) | weights bf16 (0.5 MB)  -> ~160.5 MB
    char* ws = (char*)d_ws;
    float* e = (float*)ws;
    float* t = (float*)(ws + 16777216);
    u16* wbf = (u16*)(ws + 167772160);

    k_wconv<<<1024, 256, 0, stream>>>(wqkv, wo, w1, w2, wbf);
    k_embed<<<16384, 256, 0, stream>>>(x, emb_w, emb_b, e);
    k_build<<<36864, 256, 0, stream>>>(e, pos, t);
    for (int l = 0; l < 2; ++l) {
        k_attn<<<NBLK, 256, 0, stream>>>(t, wbf + l * 49152, bqkv + l * 384,
                                         wbf + 98304 + l * 16384, bo + l * 128,
                                         ln1g + l * 128, ln1b + l * 128);
        k_ffn<<<NBLK, 256, 0, stream>>>(t, wbf + 131072 + l * 32768, b1 + l * 256,
                                        wbf + 196608 + l * 32768, b2 + l * 128,
                                        ln2g + l * 128, ln2b + l * 128);
    }
    k_head<<<2048, 256, 0, stream>>>(t, lnfg, lnfb, headw, headb, out);
}

// Round 4
// 896.770 us; speedup vs baseline: 1.2294x; 1.2294x over previous
//
#include <hip/hip_runtime.h>
#include <hip/hip_bf16.h>

typedef unsigned short u16;
typedef unsigned int   u32;
typedef __attribute__((ext_vector_type(8))) short bf16x8;
typedef __attribute__((ext_vector_type(4))) float f32x4;

#define NTOK 32768
#define TPB  4          // tokens per block
#define MR   36         // real rows per block (TPB*9)
#define MPAD 48         // padded to 3 MFMA M-tiles
#define NBLK (NTOK/TPB) // 8192

// k_attn LDS layout (bytes): qk [48][512] (q|k bf16) | vt [4][2][128][8] bf16 (v^T) | hb [48][256] bf16
#define QK_OFF 0
#define VT_OFF 24576
#define HB_OFF 40960
#define SM_ATTN 53248

__device__ __forceinline__ float bf2f(u16 u) {
    u32 x = ((u32)u) << 16; float f; __builtin_memcpy(&f, &x, 4); return f;
}
__device__ __forceinline__ u16 f2bf(float f) {
    u32 u; __builtin_memcpy(&u, &f, 4);
    u32 r = (u + 0x7fffu + ((u >> 16) & 1u)) >> 16;
    return (u16)r;
}
__device__ __forceinline__ u32 packbf(float a, float b) {
    return (u32)f2bf(a) | ((u32)f2bf(b) << 16);
}
__device__ __forceinline__ float wredsum(float v) {
#pragma unroll
    for (int m = 32; m >= 1; m >>= 1) v += __shfl_xor(v, m, 64);
    return v;
}
// gelu(x) = 0.5x(1+erf(x/sqrt2)); erf via Abramowitz-Stegun 7.1.26 (|err|<=1.5e-7)
__device__ __forceinline__ float gelu_f(float x) {
    float ax = fabsf(x) * 0.70710678118654752f;   // |x|/sqrt(2)  <-- the round-3 bug was missing this scale
    float tt = __builtin_amdgcn_rcpf(1.0f + 0.3275911f * ax);
    float poly = tt * (0.254829592f + tt * (-0.284496736f + tt * (1.421413741f +
                 tt * (-1.453152027f + tt * 1.061405429f))));
    float er = 1.0f - poly * __expf(-ax * ax);
    er = copysignf(er, x);
    return 0.5f * x * (1.0f + er);
}

// ---------------- weight fp32 -> bf16 ----------------
// wbf: [0,98304) wqkv | [98304,131072) wo | [131072,196608) w1 | [196608,262144) w2
__global__ __launch_bounds__(256) void k_wconv(const float* __restrict__ wqkv, const float* __restrict__ wo,
                                               const float* __restrict__ w1, const float* __restrict__ w2,
                                               u16* __restrict__ wbf) {
    int i = blockIdx.x * 256 + threadIdx.x;
    float v;
    if (i < 98304)       v = wqkv[i];
    else if (i < 131072) v = wo[i - 98304];
    else if (i < 196608) v = w1[i - 131072];
    else                 v = w2[i - 196608];
    wbf[i] = f2bf(v);
}

// ---------------- embedding ----------------
__global__ __launch_bounds__(256) void k_embed(const float* __restrict__ x, const float* __restrict__ ew,
                                               const float* __restrict__ eb, float* __restrict__ e) {
    int idx = blockIdx.x * 256 + threadIdx.x;
    int d = idx & 127, pix = idx >> 7;
    int b = pix >> 14, hw = pix & 16383;
    const float* xp = x + b * 262144 + hw;
    const float* wr = ew + d * 16;
    float acc = eb[d];
#pragma unroll
    for (int c = 0; c < 16; ++c) acc += xp[c * 16384] * wr[c];
    e[idx] = acc;
}

// ---------------- window gather + pos ----------------
__global__ __launch_bounds__(256) void k_build(const float* __restrict__ e, const float* __restrict__ pos,
                                               float* __restrict__ t) {
    int id = blockIdx.x * 256 + threadIdx.x;
    int c4 = (id & 31) << 2;
    int np = id >> 5;
    int p = np % 9;
    int n = np / 9;
    int b = n >> 14, h = (n >> 7) & 127, w = n & 127;
    int sh = h + p / 3 - 1, sw = w + p % 3 - 1;
    float4 v = {0.f, 0.f, 0.f, 0.f};
    if (sh >= 0 && sh < 128 && sw >= 0 && sw < 128)
        v = *(const float4*)(e + (size_t)((b << 14) + (sh << 7) + sw) * 128 + c4);
    float4 pv = *(const float4*)(pos + p * 128 + c4);
    v.x += pv.x; v.y += pv.y; v.z += pv.z; v.w += pv.w;
    *(float4*)(t + (size_t)np * 128 + c4) = v;
}

// ---------------- layer part 1: LN1 + qkv + attention (MFMA PV) + wo + residual ----------------
__global__ __launch_bounds__(512, 6) void k_attn(
    float* __restrict__ t,
    const u16* __restrict__ wq, const float* __restrict__ bq,
    const u16* __restrict__ wov, const float* __restrict__ bov,
    const float* __restrict__ lg, const float* __restrict__ lb) {
    __shared__ char smem[SM_ATTN];
    char* qk = smem + QK_OFF;
    char* vt = smem + VT_OFF;
    char* hb = smem + HB_OFF;
    const int tid = threadIdx.x, lane = tid & 63, wid = tid >> 6;
    const int blk = blockIdx.x;
    const int col = lane & 15, grp = lane >> 4;
    const f32x4 zero4 = {0.f, 0.f, 0.f, 0.f};

    // zero v^T buffer (unwritten j-slots must be exact 0 for PV MFMA)
    *(f32x4*)(vt + tid * 32) = zero4;
    *(f32x4*)(vt + tid * 32 + 16) = zero4;
    // zero hb pad rows 36..47
    if (tid < 192) {
        int pr = MR + (tid >> 4), pc = (tid & 15) * 16;
        *(f32x4*)(hb + pr * 256 + (pc ^ ((pr & 7) << 4))) = zero4;
    }
    // Phase 1: LayerNorm -> hb (bf16)
    {
        float2 gv = ((const float2*)lg)[lane];
        float2 bv = ((const float2*)lb)[lane];
        for (int r = wid; r < MR; r += 8) {
            const float2* tr = (const float2*)(t + ((size_t)blk * MR + r) * 128);
            float2 xv = tr[lane];
            float mean = wredsum(xv.x + xv.y) * (1.f / 128.f);
            float var  = wredsum(xv.x * xv.x + xv.y * xv.y) * (1.f / 128.f) - mean * mean;
            float rstd = rsqrtf(var + 1e-5f);
            float h0 = (xv.x - mean) * rstd * gv.x + bv.x;
            float h1 = (xv.y - mean) * rstd * gv.y + bv.y;
            u32 pk = packbf(h0, h1);
            *(u32*)(hb + r * 256 + ((lane * 4) ^ ((r & 7) << 4))) = pk;
        }
    }
    __syncthreads();
    // Phase 2: qkv GEMM (M=48, N=384, K=128). q scaled; v written transposed to vt.
    for (int nt = 0; nt < 3; ++nt) {
        int n0 = (wid * 3 + nt) * 16;
        int nr = n0 + col;
        bf16x8 bfr[4];
        const u16* wr = wq + nr * 128 + grp * 8;
#pragma unroll
        for (int ks = 0; ks < 4; ++ks) bfr[ks] = *(const bf16x8*)(wr + ks * 32);
        float bias = bq[nr];
        float scl = (n0 < 128) ? 0.17677669529663687f : 1.0f;
        bool isv = (n0 >= 256);
        for (int mt = 0; mt < 3; ++mt) {
            f32x4 acc = zero4;
#pragma unroll
            for (int ks = 0; ks < 4; ++ks) {
                int row = mt * 16 + col;
                bf16x8 a = *(const bf16x8*)(hb + row * 256 + ((ks * 64 + grp * 16) ^ ((row & 7) << 4)));
                acc = __builtin_amdgcn_mfma_f32_16x16x32_bf16(a, bfr[ks], acc, 0, 0, 0);
            }
#pragma unroll
            for (int j = 0; j < 4; ++j) {
                int R = mt * 16 + grp * 4 + j;
                float v = (acc[j] + bias) * scl;
                if (!isv) {
                    *(u16*)(qk + R * 512 + ((nr * 2) ^ ((R & 7) << 4))) = f2bf(v);
                } else if (R < MR) {
                    int tok = R / 9, jp = R % 9;
                    int d = nr - 256;
                    *(u16*)(vt + tok * 4096 + (jp >> 3) * 2048 + d * 16 + (jp & 7) * 2) = f2bf(v);
                }
            }
        }
    }
    __syncthreads();
    // Phase 3: attention. 16 (token,head) pairs over 8 waves; all-MFMA QK^T and PV.
    for (int i = 0; i < 2; ++i) {
        int pair = wid * 2 + i;
        int tok = pair >> 2, head = pair & 3;
        int rb = tok * 9;
        // S^T = mfma(K, Q): lane(col,grp) reg r holds S[q=col][j=grp*4+r]
        int rm = rb + (col < 9 ? col : 8);
        bf16x8 kf = *(const bf16x8*)(qk + rm * 512 + ((256 + head * 64 + grp * 16) ^ ((rm & 7) << 4)));
        bf16x8 qf = *(const bf16x8*)(qk + rm * 512 + ((head * 64 + grp * 16) ^ ((rm & 7) << 4)));
        f32x4 s = __builtin_amdgcn_mfma_f32_16x16x32_bf16(kf, qf, zero4, 0, 0, 0);
        int jb = grp * 4;
        float mx = -1e30f;
#pragma unroll
        for (int r = 0; r < 4; ++r) if (jb + r < 9) mx = fmaxf(mx, s[r]);
        mx = fmaxf(mx, __shfl_xor(mx, 16, 64));
        mx = fmaxf(mx, __shfl_xor(mx, 32, 64));
        float e0[4], ss = 0.f;
#pragma unroll
        for (int r = 0; r < 4; ++r) { e0[r] = (jb + r < 9) ? __expf(s[r] - mx) : 0.f; ss += e0[r]; }
        ss += __shfl_xor(ss, 16, 64);
        ss += __shfl_xor(ss, 32, 64);
        float rinv = __builtin_amdgcn_rcpf(ss);
        // build att B-fragment: dest lane(n=q,g') needs att[q][8g'..8g'+7]
        u32 p0 = packbf(e0[0] * rinv, e0[1] * rinv);
        u32 p1 = packbf(e0[2] * rinv, e0[3] * rinv);
        int idx0 = (col + 32 * grp) * 4;
        u32 w0 = (u32)__builtin_amdgcn_ds_bpermute(idx0, (int)p0);
        u32 w1 = (u32)__builtin_amdgcn_ds_bpermute(idx0, (int)p1);
        u32 w2 = (u32)__builtin_amdgcn_ds_bpermute(idx0 + 64, (int)p0);
        u32 w3 = (u32)__builtin_amdgcn_ds_bpermute(idx0 + 64, (int)p1);
        if (grp >= 2) { w0 = 0; w1 = 0; w2 = 0; w3 = 0; } // k>=16 -> zero
        union { u32 w[4]; bf16x8 v; } bu;
        bu.w[0] = w0; bu.w[1] = w1; bu.w[2] = w2; bu.w[3] = w3;
#pragma unroll
        for (int dh = 0; dh < 2; ++dh) {
            // A = v^T rows d = head*32+dh*16+m, k=j
            bf16x8 af = *(const bf16x8*)(vt + tok * 4096 + (grp & 1) * 2048 + (head * 32 + dh * 16 + col) * 16);
            f32x4 o = __builtin_amdgcn_mfma_f32_16x16x32_bf16(af, bu.v, zero4, 0, 0, 0);
            // lane(col,grp) reg r: o[q=col][d = head*32+dh*16+grp*4+r]
            if (col < 9) {
                int row = rb + col;
#pragma unroll
                for (int r = 0; r < 4; ++r)
                    *(u16*)(hb + row * 256 + ((head * 64 + dh * 32 + grp * 8 + r * 2) ^ ((row & 7) << 4))) = f2bf(o[r]);
            }
        }
    }
    __syncthreads();
    // Phase 4: wo GEMM + residual (each of 8 waves owns one 16-col tile)
    {
        int nr = wid * 16 + col;
        bf16x8 bw[4];
        const u16* wr = wov + nr * 128 + grp * 8;
#pragma unroll
        for (int ks = 0; ks < 4; ++ks) bw[ks] = *(const bf16x8*)(wr + ks * 32);
        float bias = bov[nr];
        for (int mt = 0; mt < 3; ++mt) {
            f32x4 acc = zero4;
#pragma unroll
            for (int ks = 0; ks < 4; ++ks) {
                int row = mt * 16 + col;
                bf16x8 a = *(const bf16x8*)(hb + row * 256 + ((ks * 64 + grp * 16) ^ ((row & 7) << 4)));
                acc = __builtin_amdgcn_mfma_f32_16x16x32_bf16(a, bw[ks], acc, 0, 0, 0);
            }
#pragma unroll
            for (int j = 0; j < 4; ++j) {
                int R = mt * 16 + grp * 4 + j;
                if (R < MR) {
                    float* p = t + ((size_t)blk * MR + R) * 128 + nr;
                    *p = acc[j] + bias + *p;
                }
            }
        }
    }
}

// ---------------- layer part 2: LN2 + FFN + residual ----------------
__global__ __launch_bounds__(512, 6) void k_ffn(
    float* __restrict__ t,
    const u16* __restrict__ w1w, const float* __restrict__ b1v,
    const u16* __restrict__ w2w, const float* __restrict__ b2v,
    const float* __restrict__ lg, const float* __restrict__ lb) {
    __shared__ char smem[36864];
    char* hb  = smem;          // bf16[48][128]
    char* mid = smem + 12288;  // bf16[48][256]
    const int tid = threadIdx.x, lane = tid & 63, wid = tid >> 6;
    const int blk = blockIdx.x;
    const int col = lane & 15, grp = lane >> 4;
    const f32x4 zero4 = {0.f, 0.f, 0.f, 0.f};

    if (tid < 192) {
        int pr = MR + (tid >> 4), pc = (tid & 15) * 16;
        *(f32x4*)(hb + pr * 256 + (pc ^ ((pr & 7) << 4))) = zero4;
    }
    {
        float2 gv = ((const float2*)lg)[lane];
        float2 bv = ((const float2*)lb)[lane];
        for (int r = wid; r < MR; r += 8) {
            const float2* tr = (const float2*)(t + ((size_t)blk * MR + r) * 128);
            float2 xv = tr[lane];
            float mean = wredsum(xv.x + xv.y) * (1.f / 128.f);
            float var  = wredsum(xv.x * xv.x + xv.y * xv.y) * (1.f / 128.f) - mean * mean;
            float rstd = rsqrtf(var + 1e-5f);
            float h0 = (xv.x - mean) * rstd * gv.x + bv.x;
            float h1 = (xv.y - mean) * rstd * gv.y + bv.y;
            u32 pk = packbf(h0, h1);
            *(u32*)(hb + r * 256 + ((lane * 4) ^ ((r & 7) << 4))) = pk;
        }
    }
    __syncthreads();
    // GEMM1: M=48, N=256, K=128 + gelu -> mid
    for (int nt = 0; nt < 2; ++nt) {
        int n0 = (wid * 2 + nt) * 16;
        int nr = n0 + col;
        bf16x8 bfr[4];
        const u16* wr = w1w + nr * 128 + grp * 8;
#pragma unroll
        for (int ks = 0; ks < 4; ++ks) bfr[ks] = *(const bf16x8*)(wr + ks * 32);
        float bias = b1v[nr];
        for (int mt = 0; mt < 3; ++mt) {
            f32x4 acc = zero4;
#pragma unroll
            for (int ks = 0; ks < 4; ++ks) {
                int row = mt * 16 + col;
                bf16x8 a = *(const bf16x8*)(hb + row * 256 + ((ks * 64 + grp * 16) ^ ((row & 7) << 4)));
                acc = __builtin_amdgcn_mfma_f32_16x16x32_bf16(a, bfr[ks], acc, 0, 0, 0);
            }
#pragma unroll
            for (int j = 0; j < 4; ++j) {
                int R = mt * 16 + grp * 4 + j;
                float ge = gelu_f(acc[j] + bias);
                *(u16*)(mid + R * 512 + ((nr * 2) ^ ((R & 7) << 4))) = f2bf(ge);
            }
        }
    }
    __syncthreads();
    // GEMM2: M=48, N=128, K=256 + residual
    {
        int nr = wid * 16 + col;
        bf16x8 bfr[8];
        const u16* wr = w2w + nr * 256 + grp * 8;
#pragma unroll
        for (int ks = 0; ks < 8; ++ks) bfr[ks] = *(const bf16x8*)(wr + ks * 32);
        float bias = b2v[nr];
        for (int mt = 0; mt < 3; ++mt) {
            f32x4 acc = zero4;
#pragma unroll
            for (int ks = 0; ks < 8; ++ks) {
                int row = mt * 16 + col;
                bf16x8 a = *(const bf16x8*)(mid + row * 512 + ((ks * 64 + grp * 16) ^ ((row & 7) << 4)));
                acc = __builtin_amdgcn_mfma_f32_16x16x32_bf16(a, bfr[ks], acc, 0, 0, 0);
            }
#pragma unroll
            for (int j = 0; j < 4; ++j) {
                int R = mt * 16 + grp * 4 + j;
                if (R < MR) {
                    float* p = t + ((size_t)blk * MR + R) * 128 + nr;
                    *p = acc[j] + bias + *p;
                }
            }
        }
    }
}

// ---------------- final: center LN + head ----------------
__global__ __launch_bounds__(256) void k_head(const float* __restrict__ t, const float* __restrict__ g,
                                              const float* __restrict__ b, const float* __restrict__ hw,
                                              const float* __restrict__ hbias, float* __restrict__ out) {
    int lane = threadIdx.x & 63, wid = threadIdx.x >> 6;
    int base = blockIdx.x * 16 + wid * 4;
    float2 gv = ((const float2*)g)[lane];
    float2 bv = ((const float2*)b)[lane];
    float2 wv = ((const float2*)hw)[lane];
    float hb0 = hbias[0];
    for (int it = 0; it < 4; ++it) {
        int n = base + it;
        const float2* row = (const float2*)(t + ((size_t)n * 9 + 4) * 128);
        float2 xv = row[lane];
        float mean = wredsum(xv.x + xv.y) * (1.f / 128.f);
        float var  = wredsum(xv.x * xv.x + xv.y * xv.y) * (1.f / 128.f) - mean * mean;
        float rstd = rsqrtf(var + 1e-5f);
        float v = ((xv.x - mean) * rstd * gv.x + bv.x) * wv.x +
                  ((xv.y - mean) * rstd * gv.y + bv.y) * wv.y;
        v = wredsum(v);
        if (lane == 0) out[n] = v + hb0;
    }
}

extern "C" void kernel_launch(void* const* d_in, const int* in_sizes, int n_in,
                              void* d_out, int out_size, void* d_ws, size_t ws_size,
                              hipStream_t stream) {
    (void)in_sizes; (void)n_in; (void)out_size; (void)ws_size;
    const float* x     = (const float*)d_in[0];
    const float* emb_w = (const float*)d_in[1];
    const float* emb_b = (const float*)d_in[2];
    const float* pos   = (const float*)d_in[3];
    const float* wqkv  = (const float*)d_in[4];
    const float* bqkv  = (const float*)d_in[5];
    const float* wo    = (const float*)d_in[6];
    const float* bo    = (const float*)d_in[7];
    const float* ln1g  = (const float*)d_in[8];
    const float* ln1b  = (const float*)d_in[9];
    const float* ln2g  = (const float*)d_in[10];
    const float* ln2b  = (const float*)d_in[11];
    const float* w1    = (const float*)d_in[12];
    const float* b1    = (const float*)d_in[13];
    const float* w2    = (const float*)d_in[14];
    const float* b2    = (const float*)d_in[15];
    const float* lnfg  = (const float*)d_in[16];
    const float* lnfb  = (const float*)d_in[17];
    const float* headw = (const float*)d_in[18];
    const float* headb = (const float*)d_in[19];
    float* out = (float*)d_out;

    char* ws = (char*)d_ws;
    float* e = (float*)ws;                       // 16 MB
    float* t = (float*)(ws + 16777216);          // 151 MB
    u16* wbf = (u16*)(ws + 167772160);           // 0.5 MB

    k_wconv<<<1024, 256, 0, stream>>>(wqkv, wo, w1, w2, wbf);
    k_embed<<<16384, 256, 0, stream>>>(x, emb_w, emb_b, e);
    k_build<<<36864, 256, 0, stream>>>(e, pos, t);
    for (int l = 0; l < 2; ++l) {
        k_attn<<<NBLK, 512, 0, stream>>>(t, wbf + l * 49152, bqkv + l * 384,
                                         wbf + 98304 + l * 16384, bo + l * 128,
                                         ln1g + l * 128, ln1b + l * 128);
        k_ffn<<<NBLK, 512, 0, stream>>>(t, wbf + 131072 + l * 32768, b1 + l * 256,
                                        wbf + 196608 + l * 32768, b2 + l * 128,
                                        ln2g + l * 128, ln2b + l * 128);
    }
    k_head<<<2048, 256, 0, stream>>>(t, lnfg, lnfb, headw, headb, out);
}

// Round 12
// 886.986 us; speedup vs baseline: 1.2430x; 1.0110x over previous
//
#include <hip/hip_runtime.h>
#include <hip/hip_bf16.h>

typedef unsigned short u16;
typedef unsigned int   u32;
typedef __attribute__((ext_vector_type(8))) short bf16x8;
typedef __attribute__((ext_vector_type(4))) float f32x4;
typedef __attribute__((ext_vector_type(2))) unsigned int u32x2;

#define NTOK 32768
#define TPB  4          // tokens per block
#define MR   36         // real rows per block (TPB*9)
#define MPAD 48         // padded to 3 MFMA M-tiles
#define NBLK (NTOK/TPB) // 8192

// k_attn LDS layout (bytes): qk [48][512] (q|k bf16) | vt [4][2][128][8] bf16 (v^T) | hb [48][256] bf16
#define QK_OFF 0
#define VT_OFF 24576
#define HB_OFF 40960
#define SM_ATTN 53248

// scalar f32->bf16, RNE (manual bit-twiddle — known-good from the measured round-4 kernel)
__device__ __forceinline__ u16 f2bf(float f) {
    u32 u; __builtin_memcpy(&u, &f, 4);
    u32 r = (u + 0x7fffu + ((u >> 16) & 1u)) >> 16;
    return (u16)r;
}
// packed pair f32->bf16x2 via HIP intrinsic (RNE; compiler-generated encoding, NOT raw asm)
__device__ __forceinline__ u32 packbf2(float a, float b) {
    __hip_bfloat162 h = __float22bfloat162_rn(make_float2(a, b));
    u32 r; __builtin_memcpy(&r, &h, 4); return r;   // .x in low 16 bits, .y in high
}
__device__ __forceinline__ float wredsum(float v) {
#pragma unroll
    for (int m = 32; m >= 1; m >>= 1) v += __shfl_xor(v, m, 64);
    return v;
}
// gelu(x) = 0.5x(1+erf(x/sqrt2)); erf via Abramowitz-Stegun 7.1.26 (|err|<=1.5e-7)
__device__ __forceinline__ float gelu_f(float x) {
    float ax = fabsf(x) * 0.70710678118654752f;
    float tt = __builtin_amdgcn_rcpf(1.0f + 0.3275911f * ax);
    float poly = tt * (0.254829592f + tt * (-0.284496736f + tt * (1.421413741f +
                 tt * (-1.453152027f + tt * 1.061405429f))));
    float er = 1.0f - poly * __expf(-ax * ax);
    er = copysignf(er, x);
    return 0.5f * x * (1.0f + er);
}

// ---------------- weight fp32 -> bf16 ----------------
__global__ __launch_bounds__(256) void k_wconv(const float* __restrict__ wqkv, const float* __restrict__ wo,
                                               const float* __restrict__ w1, const float* __restrict__ w2,
                                               u16* __restrict__ wbf) {
    int i = blockIdx.x * 256 + threadIdx.x;
    float v;
    if (i < 98304)       v = wqkv[i];
    else if (i < 131072) v = wo[i - 98304];
    else if (i < 196608) v = w1[i - 131072];
    else                 v = w2[i - 196608];
    wbf[i] = f2bf(v);
}

// ---------------- embedding ----------------
__global__ __launch_bounds__(256) void k_embed(const float* __restrict__ x, const float* __restrict__ ew,
                                               const float* __restrict__ eb, float* __restrict__ e) {
    int idx = blockIdx.x * 256 + threadIdx.x;
    int d = idx & 127, pix = idx >> 7;
    int b = pix >> 14, hw = pix & 16383;
    const float* xp = x + b * 262144 + hw;
    const float* wr = ew + d * 16;
    float acc = eb[d];
#pragma unroll
    for (int c = 0; c < 16; ++c) acc += xp[c * 16384] * wr[c];
    e[idx] = acc;
}

// ---------------- window gather + pos ----------------
__global__ __launch_bounds__(256) void k_build(const float* __restrict__ e, const float* __restrict__ pos,
                                               float* __restrict__ t) {
    int id = blockIdx.x * 256 + threadIdx.x;
    int c4 = (id & 31) << 2;
    int np = id >> 5;
    int p = np % 9;
    int n = np / 9;
    int b = n >> 14, h = (n >> 7) & 127, w = n & 127;
    int sh = h + p / 3 - 1, sw = w + p % 3 - 1;
    float4 v = {0.f, 0.f, 0.f, 0.f};
    if (sh >= 0 && sh < 128 && sw >= 0 && sw < 128)
        v = *(const float4*)(e + (size_t)((b << 14) + (sh << 7) + sw) * 128 + c4);
    float4 pv = *(const float4*)(pos + p * 128 + c4);
    v.x += pv.x; v.y += pv.y; v.z += pv.z; v.w += pv.w;
    *(float4*)(t + (size_t)np * 128 + c4) = v;
}

// ---------------- layer part 1: LN1 + qkv + attention (MFMA PV) + wo + residual ----------------
// Structure identical to the measured-passing round-4 kernel; deltas: packbf2 intrinsic for
// pair converts (LN store, P fragment, attn output) + byte-equivalent packed phase-3 store.
__global__ __launch_bounds__(512, 6) void k_attn(
    float* __restrict__ t,
    const u16* __restrict__ wq, const float* __restrict__ bq,
    const u16* __restrict__ wov, const float* __restrict__ bov,
    const float* __restrict__ lg, const float* __restrict__ lb) {
    __shared__ char smem[SM_ATTN];
    char* qk = smem + QK_OFF;
    char* vt = smem + VT_OFF;
    char* hb = smem + HB_OFF;
    const int tid = threadIdx.x, lane = tid & 63, wid = tid >> 6;
    const int blk = blockIdx.x;
    const int col = lane & 15, grp = lane >> 4;
    const f32x4 zero4 = {0.f, 0.f, 0.f, 0.f};

    // zero v^T buffer (unwritten j-slots must be exact 0 for PV MFMA)
    *(f32x4*)(vt + tid * 32) = zero4;
    *(f32x4*)(vt + tid * 32 + 16) = zero4;
    // zero hb pad rows 36..47
    if (tid < 192) {
        int pr = MR + (tid >> 4), pc = (tid & 15) * 16;
        *(f32x4*)(hb + pr * 256 + (pc ^ ((pr & 7) << 4))) = zero4;
    }
    // Phase 1: LayerNorm -> hb (bf16)
    {
        float2 gv = ((const float2*)lg)[lane];
        float2 bv = ((const float2*)lb)[lane];
        for (int r = wid; r < MR; r += 8) {
            const float2* tr = (const float2*)(t + ((size_t)blk * MR + r) * 128);
            float2 xv = tr[lane];
            float mean = wredsum(xv.x + xv.y) * (1.f / 128.f);
            float var  = wredsum(xv.x * xv.x + xv.y * xv.y) * (1.f / 128.f) - mean * mean;
            float rstd = rsqrtf(var + 1e-5f);
            float h0 = (xv.x - mean) * rstd * gv.x + bv.x;
            float h1 = (xv.y - mean) * rstd * gv.y + bv.y;
            *(u32*)(hb + r * 256 + ((lane * 4) ^ ((r & 7) << 4))) = packbf2(h0, h1);
        }
    }
    __syncthreads();
    // Phase 2: qkv GEMM (M=48, N=384, K=128). q gets bias then *scale; v -> vt transposed.
    for (int nt = 0; nt < 3; ++nt) {
        int n0 = (wid * 3 + nt) * 16;
        int nr = n0 + col;
        bf16x8 bfr[4];
        const u16* wr = wq + nr * 128 + grp * 8;
#pragma unroll
        for (int ks = 0; ks < 4; ++ks) bfr[ks] = *(const bf16x8*)(wr + ks * 32);
        float bias = bq[nr];
        float scl = (n0 < 128) ? 0.17677669529663687f : 1.0f;
        bool isv = (n0 >= 256);
        for (int mt = 0; mt < 3; ++mt) {
            f32x4 acc = zero4;
#pragma unroll
            for (int ks = 0; ks < 4; ++ks) {
                int row = mt * 16 + col;
                bf16x8 a = *(const bf16x8*)(hb + row * 256 + ((ks * 64 + grp * 16) ^ ((row & 7) << 4)));
                acc = __builtin_amdgcn_mfma_f32_16x16x32_bf16(a, bfr[ks], acc, 0, 0, 0);
            }
#pragma unroll
            for (int j = 0; j < 4; ++j) {
                int R = mt * 16 + grp * 4 + j;
                float v = (acc[j] + bias) * scl;
                if (!isv) {
                    *(u16*)(qk + R * 512 + ((nr * 2) ^ ((R & 7) << 4))) = f2bf(v);
                } else if (R < MR) {
                    int tok = R / 9, jp = R % 9;
                    int d = nr - 256;
                    *(u16*)(vt + tok * 4096 + (jp >> 3) * 2048 + d * 16 + (jp & 7) * 2) = f2bf(v);
                }
            }
        }
    }
    __syncthreads();
    // Phase 3: attention. 16 (token,head) pairs over 8 waves; all-MFMA QK^T and PV.
    for (int i = 0; i < 2; ++i) {
        int pair = wid * 2 + i;
        int tok = pair >> 2, head = pair & 3;
        int rb = tok * 9;
        // S^T = mfma(K, Q): lane(col,grp) reg r holds S[q=col][j=grp*4+r]
        int rm = rb + (col < 9 ? col : 8);
        bf16x8 kf = *(const bf16x8*)(qk + rm * 512 + ((256 + head * 64 + grp * 16) ^ ((rm & 7) << 4)));
        bf16x8 qf = *(const bf16x8*)(qk + rm * 512 + ((head * 64 + grp * 16) ^ ((rm & 7) << 4)));
        f32x4 s = __builtin_amdgcn_mfma_f32_16x16x32_bf16(kf, qf, zero4, 0, 0, 0);
        int jb = grp * 4;
        float mx = -1e30f;
#pragma unroll
        for (int r = 0; r < 4; ++r) if (jb + r < 9) mx = fmaxf(mx, s[r]);
        mx = fmaxf(mx, __shfl_xor(mx, 16, 64));
        mx = fmaxf(mx, __shfl_xor(mx, 32, 64));
        float e0[4], ss = 0.f;
#pragma unroll
        for (int r = 0; r < 4; ++r) { e0[r] = (jb + r < 9) ? __expf(s[r] - mx) : 0.f; ss += e0[r]; }
        ss += __shfl_xor(ss, 16, 64);
        ss += __shfl_xor(ss, 32, 64);
        float rinv = __builtin_amdgcn_rcpf(ss);
        // build att B-fragment: dest lane(n=q,g') needs att[q][8g'..8g'+7]
        u32 p0 = packbf2(e0[0] * rinv, e0[1] * rinv);
        u32 p1 = packbf2(e0[2] * rinv, e0[3] * rinv);
        int idx0 = (col + 32 * grp) * 4;
        u32 w0 = (u32)__builtin_amdgcn_ds_bpermute(idx0, (int)p0);
        u32 w1 = (u32)__builtin_amdgcn_ds_bpermute(idx0, (int)p1);
        u32 w2 = (u32)__builtin_amdgcn_ds_bpermute(idx0 + 64, (int)p0);
        u32 w3 = (u32)__builtin_amdgcn_ds_bpermute(idx0 + 64, (int)p1);
        if (grp >= 2) { w0 = 0; w1 = 0; w2 = 0; w3 = 0; } // k>=16 -> zero
        union { u32 w[4]; bf16x8 v; } bu;
        bu.w[0] = w0; bu.w[1] = w1; bu.w[2] = w2; bu.w[3] = w3;
#pragma unroll
        for (int dh = 0; dh < 2; ++dh) {
            bf16x8 af = *(const bf16x8*)(vt + tok * 4096 + (grp & 1) * 2048 + (head * 32 + dh * 16 + col) * 16);
            f32x4 o = __builtin_amdgcn_mfma_f32_16x16x32_bf16(af, bu.v, zero4, 0, 0, 0);
            // lane(col,grp) reg r: o[q=col][d = head*32+dh*16+grp*4+r] -> 4 consecutive bf16.
            // Packed b64 store hits the exact bytes the round-4 scalar stores hit:
            // swizzle XOR touches bits 4-6, r*2 touches bits 1-2, base is 8-aligned.
            if (col < 9) {
                int row = rb + col;
                u32x2 pk; pk.x = packbf2(o[0], o[1]); pk.y = packbf2(o[2], o[3]);
                *(u32x2*)(hb + row * 256 + ((head * 64 + dh * 32 + grp * 8) ^ ((row & 7) << 4))) = pk;
            }
        }
    }
    __syncthreads();
    // Phase 4: wo GEMM + residual (each of 8 waves owns one 16-col tile; original operand order)
    {
        int nr = wid * 16 + col;
        bf16x8 bw[4];
        const u16* wr = wov + nr * 128 + grp * 8;
#pragma unroll
        for (int ks = 0; ks < 4; ++ks) bw[ks] = *(const bf16x8*)(wr + ks * 32);
        float bias = bov[nr];
        for (int mt = 0; mt < 3; ++mt) {
            f32x4 acc = zero4;
#pragma unroll
            for (int ks = 0; ks < 4; ++ks) {
                int row = mt * 16 + col;
                bf16x8 a = *(const bf16x8*)(hb + row * 256 + ((ks * 64 + grp * 16) ^ ((row & 7) << 4)));
                acc = __builtin_amdgcn_mfma_f32_16x16x32_bf16(a, bw[ks], acc, 0, 0, 0);
            }
#pragma unroll
            for (int j = 0; j < 4; ++j) {
                int R = mt * 16 + grp * 4 + j;
                if (R < MR) {
                    float* p = t + ((size_t)blk * MR + R) * 128 + nr;
                    *p = acc[j] + bias + *p;
                }
            }
        }
    }
}

// ---------------- layer part 2: LN2 + FFN + residual ----------------
__global__ __launch_bounds__(512, 6) void k_ffn(
    float* __restrict__ t,
    const u16* __restrict__ w1w, const float* __restrict__ b1v,
    const u16* __restrict__ w2w, const float* __restrict__ b2v,
    const float* __restrict__ lg, const float* __restrict__ lb) {
    __shared__ char smem[36864];
    char* hb  = smem;          // bf16[48][128]
    char* mid = smem + 12288;  // bf16[48][256]
    const int tid = threadIdx.x, lane = tid & 63, wid = tid >> 6;
    const int blk = blockIdx.x;
    const int col = lane & 15, grp = lane >> 4;
    const f32x4 zero4 = {0.f, 0.f, 0.f, 0.f};

    if (tid < 192) {
        int pr = MR + (tid >> 4), pc = (tid & 15) * 16;
        *(f32x4*)(hb + pr * 256 + (pc ^ ((pr & 7) << 4))) = zero4;
    }
    {
        float2 gv = ((const float2*)lg)[lane];
        float2 bv = ((const float2*)lb)[lane];
        for (int r = wid; r < MR; r += 8) {
            const float2* tr = (const float2*)(t + ((size_t)blk * MR + r) * 128);
            float2 xv = tr[lane];
            float mean = wredsum(xv.x + xv.y) * (1.f / 128.f);
            float var  = wredsum(xv.x * xv.x + xv.y * xv.y) * (1.f / 128.f) - mean * mean;
            float rstd = rsqrtf(var + 1e-5f);
            float h0 = (xv.x - mean) * rstd * gv.x + bv.x;
            float h1 = (xv.y - mean) * rstd * gv.y + bv.y;
            *(u32*)(hb + r * 256 + ((lane * 4) ^ ((r & 7) << 4))) = packbf2(h0, h1);
        }
    }
    __syncthreads();
    // GEMM1: M=48, N=256, K=128 + gelu -> mid (original operand order, scalar stores)
    for (int nt = 0; nt < 2; ++nt) {
        int n0 = (wid * 2 + nt) * 16;
        int nr = n0 + col;
        bf16x8 bfr[4];
        const u16* wr = w1w + nr * 128 + grp * 8;
#pragma unroll
        for (int ks = 0; ks < 4; ++ks) bfr[ks] = *(const bf16x8*)(wr + ks * 32);
        float bias = b1v[nr];
        for (int mt = 0; mt < 3; ++mt) {
            f32x4 acc = zero4;
#pragma unroll
            for (int ks = 0; ks < 4; ++ks) {
                int row = mt * 16 + col;
                bf16x8 a = *(const bf16x8*)(hb + row * 256 + ((ks * 64 + grp * 16) ^ ((row & 7) << 4)));
                acc = __builtin_amdgcn_mfma_f32_16x16x32_bf16(a, bfr[ks], acc, 0, 0, 0);
            }
#pragma unroll
            for (int j = 0; j < 4; ++j) {
                int R = mt * 16 + grp * 4 + j;
                float ge = gelu_f(acc[j] + bias);
                *(u16*)(mid + R * 512 + ((nr * 2) ^ ((R & 7) << 4))) = f2bf(ge);
            }
        }
    }
    __syncthreads();
    // GEMM2: M=48, N=128, K=256 + residual (original operand order, scalar residual)
    {
        int nr = wid * 16 + col;
        bf16x8 bfr[8];
        const u16* wr = w2w + nr * 256 + grp * 8;
#pragma unroll
        for (int ks = 0; ks < 8; ++ks) bfr[ks] = *(const bf16x8*)(wr + ks * 32);
        float bias = b2v[nr];
        for (int mt = 0; mt < 3; ++mt) {
            f32x4 acc = zero4;
#pragma unroll
            for (int ks = 0; ks < 8; ++ks) {
                int row = mt * 16 + col;
                bf16x8 a = *(const bf16x8*)(mid + row * 512 + ((ks * 64 + grp * 16) ^ ((row & 7) << 4)));
                acc = __builtin_amdgcn_mfma_f32_16x16x32_bf16(a, bfr[ks], acc, 0, 0, 0);
            }
#pragma unroll
            for (int j = 0; j < 4; ++j) {
                int R = mt * 16 + grp * 4 + j;
                if (R < MR) {
                    float* p = t + ((size_t)blk * MR + R) * 128 + nr;
                    *p = acc[j] + bias + *p;
                }
            }
        }
    }
}

// ---------------- final: center LN + head ----------------
__global__ __launch_bounds__(256) void k_head(const float* __restrict__ t, const float* __restrict__ g,
                                              const float* __restrict__ b, const float* __restrict__ hw,
                                              const float* __restrict__ hbias, float* __restrict__ out) {
    int lane = threadIdx.x & 63, wid = threadIdx.x >> 6;
    int base = blockIdx.x * 16 + wid * 4;
    float2 gv = ((const float2*)g)[lane];
    float2 bv = ((const float2*)b)[lane];
    float2 wv = ((const float2*)hw)[lane];
    float hb0 = hbias[0];
    for (int it = 0; it < 4; ++it) {
        int n = base + it;
        const float2* row = (const float2*)(t + ((size_t)n * 9 + 4) * 128);
        float2 xv = row[lane];
        float mean = wredsum(xv.x + xv.y) * (1.f / 128.f);
        float var  = wredsum(xv.x * xv.x + xv.y * xv.y) * (1.f / 128.f) - mean * mean;
        float rstd = rsqrtf(var + 1e-5f);
        float v = ((xv.x - mean) * rstd * gv.x + bv.x) * wv.x +
                  ((xv.y - mean) * rstd * gv.y + bv.y) * wv.y;
        v = wredsum(v);
        if (lane == 0) out[n] = v + hb0;
    }
}

extern "C" void kernel_launch(void* const* d_in, const int* in_sizes, int n_in,
                              void* d_out, int out_size, void* d_ws, size_t ws_size,
                              hipStream_t stream) {
    (void)in_sizes; (void)n_in; (void)out_size; (void)ws_size;
    const float* x     = (const float*)d_in[0];
    const float* emb_w = (const float*)d_in[1];
    const float* emb_b = (const float*)d_in[2];
    const float* pos   = (const float*)d_in[3];
    const float* wqkv  = (const float*)d_in[4];
    const float* bqkv  = (const float*)d_in[5];
    const float* wo    = (const float*)d_in[6];
    const float* bo    = (const float*)d_in[7];
    const float* ln1g  = (const float*)d_in[8];
    const float* ln1b  = (const float*)d_in[9];
    const float* ln2g  = (const float*)d_in[10];
    const float* ln2b  = (const float*)d_in[11];
    const float* w1    = (const float*)d_in[12];
    const float* b1    = (const float*)d_in[13];
    const float* w2    = (const float*)d_in[14];
    const float* b2    = (const float*)d_in[15];
    const float* lnfg  = (const float*)d_in[16];
    const float* lnfb  = (const float*)d_in[17];
    const float* headw = (const float*)d_in[18];
    const float* headb = (const float*)d_in[19];
    float* out = (float*)d_out;

    char* ws = (char*)d_ws;
    float* e = (float*)ws;                       // 16 MB
    float* t = (float*)(ws + 16777216);          // 151 MB
    u16* wbf = (u16*)(ws + 167772160);           // 0.5 MB

    k_wconv<<<1024, 256, 0, stream>>>(wqkv, wo, w1, w2, wbf);
    k_embed<<<16384, 256, 0, stream>>>(x, emb_w, emb_b, e);
    k_build<<<36864, 256, 0, stream>>>(e, pos, t);
    for (int l = 0; l < 2; ++l) {
        k_attn<<<NBLK, 512, 0, stream>>>(t, wbf + l * 49152, bqkv + l * 384,
                                         wbf + 98304 + l * 16384, bo + l * 128,
                                         ln1g + l * 128, ln1b + l * 128);
        k_ffn<<<NBLK, 512, 0, stream>>>(t, wbf + 131072 + l * 32768, b1 + l * 256,
                                        wbf + 196608 + l * 32768, b2 + l * 128,
                                        ln2g + l * 128, ln2b + l * 128);
    }
    k_head<<<2048, 256, 0, stream>>>(t, lnfg, lnfb, headw, headb, out);
}